// Round 14
// baseline (242.309 us; speedup 1.0000x reference)
//
#include <hip/hip_runtime.h>
#include <hip/hip_bf16.h>

#define B_TOT 2048
#define N_CAP 200
#define D_DIM 256
#define NT    512
#define NW    8               // waves per block
#define CPW   25              // capsules per wave (200/8, exact)
#define NB    8               // batch elements per block
#define GRID  (B_TOT / NB)    // 256 blocks = 1 per CU (LDS-enforced)
#define PFC   96              // capsules prefetched into LDS (0..95)
#define PFW   12              // per-wave capsules from prefetch (i < 12)

__device__ __forceinline__ float bf_lo(unsigned u) { return __uint_as_float(u << 16); }
__device__ __forceinline__ float bf_hi(unsigned u) { return __uint_as_float(u & 0xffff0000u); }

__device__ __forceinline__ float wave_sum(float v) {
#pragma unroll
    for (int off = 32; off; off >>= 1) v += __shfl_xor(v, off);
    return v;
}

// Block sum WITHOUT leading barrier: caller must guarantee a __syncthreads()
// executed between the previous read of red[] and this call (WAR safety).
__device__ __forceinline__ float block_sum_nb(float v, float* red, int wave, int lane) {
    v = wave_sum(v);
    if (lane == 0) red[wave] = v;
    __syncthreads();
    float s = 0.f;
#pragma unroll
    for (int i = 0; i < NW; ++i) s += red[i];
    return s;
}

// Async DMA: first 96 KB of a batch slab -> LDS pf, linear. Per round each
// wave copies 1 KB (64 lanes x 16 B); LDS dest is wave-uniform base + lane*16
// (HW rule), global src is per-lane. 12 rounds x 8 waves = 96 KB.
__device__ __forceinline__ void issue_prefetch(const float* __restrict__ slab,
                                               float* pf, int wave, int lane) {
    const char* gb = (const char*)slab;
    char* lb = (char*)pf;
#pragma unroll
    for (int rd = 0; rd < 12; ++rd) {
        const int off = rd * 8192 + wave * 1024;
        __builtin_amdgcn_global_load_lds(
            (const __attribute__((address_space(1))) void*)(gb + off + lane * 16),
            (__attribute__((address_space(3))) void*)(lb + off),
            16, 0, 0);
    }
}

// Anchor = R10 (162us best; routing proven). R14 delta: persistent blocks
// (grid 256, NB=8 b's each) + async global_load_lds prefetch of caps 0..95
// of b+1 during routing of b. 1 block/CU (LDS 107KB) -> VGPR budget 256,
// spill war over. Routing structure/math byte-identical to R10.
// DO NOT: fuse agreement+einsum accumulators (R3/R4 spill), LB(...,8)
// (R9: 32 VGPR), per-capsule sched_barrier (R6), lane-select psel gather
// (R11 wrong c), inline e*inv einsum / phase-cut tails (R12 +19us),
// 16-wave split (R13 +16us).
__global__ __launch_bounds__(NT, 2)
void dyr_kernel(const float* __restrict__ embeds,
                const float* __restrict__ weights,
                float* __restrict__ out_v,
                float* __restrict__ out_c)
{
    __shared__ __align__(16) float pf[PFC * D_DIM];   // 96 KB prefetch buffer
    __shared__ float s_part[NW][D_DIM];               // 8 KB
    __shared__ float red[NW];
    __shared__ float b_lds[N_CAP];
    __shared__ float w_lds[N_CAP];
    __shared__ float inv_lds[N_CAP];
    __shared__ float v_lds[D_DIM];

    const int t    = threadIdx.x;
    const int wave = t >> 6;
    const int lane = t & 63;
    const int b0   = blockIdx.x * NB;

    issue_prefetch(embeds + (size_t)b0 * (N_CAP * D_DIM), pf, wave, lane);

    for (int k = 0; k < NB; ++k) {
        const int b = b0 + k;
        const float* slab = embeds + (size_t)b * (N_CAP * D_DIM);

        __syncthreads();   // drains vmcnt: prefetch arrived; joins prior k

        // ---- logits init (own slot; read first by same thread) ----
        if (t < N_CAP) b_lds[t] = weights[(size_t)b * N_CAP + t];

        uint2 u[CPW];   // 50 VGPRs, raw x packed bf16

        // ---- step 1: caps 0..95 from LDS prefetch (i < 12) ----
#pragma unroll
        for (int i = 0; i < PFW; ++i) {
            const int n = wave + NW * i;
            const float4 x = *reinterpret_cast<const float4*>(&pf[n * D_DIM + lane * 4]);
            float ss = fmaf(x.x, x.x, fmaf(x.y, x.y, fmaf(x.z, x.z, x.w * x.w)));
            ss = wave_sum(ss);
            if (lane == 0) inv_lds[n] = 1.0f / fmaxf(sqrtf(ss), 1e-12f);
            union { __hip_bfloat16 h[4]; uint2 q; } pk;
            pk.h[0] = __float2bfloat16(x.x);
            pk.h[1] = __float2bfloat16(x.y);
            pk.h[2] = __float2bfloat16(x.z);
            pk.h[3] = __float2bfloat16(x.w);
            u[i] = pk.q;
        }

        // ---- step 2: caps 96..199 via global (i = 12..24), chunks {5,5,3} ----
        const float* eb = slab + lane * 4;
#pragma unroll
        for (int cc = 0; cc < 3; ++cc) {
            const int base = 12 + cc * 5;
            const int cnt  = (cc == 2) ? 3 : 5;
            float4 xs[5];
#pragma unroll
            for (int j = 0; j < 5; ++j) {
                if (j < cnt)
                    xs[j] = *reinterpret_cast<const float4*>(eb + (wave + (base + j) * NW) * D_DIM);
            }
#pragma unroll
            for (int j = 0; j < 5; ++j) {
                if (j < cnt) {
                    const int i = base + j;
                    const float4 x = xs[j];
                    float ss = fmaf(x.x, x.x, fmaf(x.y, x.y, fmaf(x.z, x.z, x.w * x.w)));
                    ss = wave_sum(ss);
                    if (lane == 0)
                        inv_lds[wave + NW * i] = 1.0f / fmaxf(sqrtf(ss), 1e-12f);
                    union { __hip_bfloat16 h[4]; uint2 q; } pk;
                    pk.h[0] = __float2bfloat16(x.x);
                    pk.h[1] = __float2bfloat16(x.y);
                    pk.h[2] = __float2bfloat16(x.z);
                    pk.h[3] = __float2bfloat16(x.w);
                    u[i] = pk.q;
                }
            }
        }
        __syncthreads();   // inv_lds/b_lds published; pf reads done block-wide

        // ---- 3 routing iterations (R10's exact phase layout) ----
        for (int r = 0; r < 3; ++r) {
            // softmax denominator (no max-subtraction; |b| <= ~8, fp32 exp safe)
            const float e  = (t < N_CAP) ? __expf(b_lds[t]) : 0.0f;
            const float es = block_sum_nb(e, red, wave, lane);
            const float cs = (float)N_CAP / es;
            if (t < N_CAP) {
                const float cv = e * cs;             // c_n = softmax * N
                w_lds[t] = cv * inv_lds[t];          // einsum weight (norm folded)
                if (r == 2) out_c[(size_t)b * N_CAP + t] = cv;
            }
            __syncthreads();                          // w_lds visible

            // einsum partial: acc = sum_i w_i * x_i
            float4 acc = make_float4(0.f, 0.f, 0.f, 0.f);
#pragma unroll
            for (int i = 0; i < CPW; ++i) {
                const float wn = w_lds[wave + NW * i];   // wave-uniform broadcast
                acc.x = fmaf(wn, bf_lo(u[i].x), acc.x);
                acc.y = fmaf(wn, bf_hi(u[i].x), acc.y);
                acc.z = fmaf(wn, bf_lo(u[i].y), acc.z);
                acc.w = fmaf(wn, bf_hi(u[i].y), acc.w);
            }
            *reinterpret_cast<float4*>(&s_part[wave][lane * 4]) = acc;
            __syncthreads();                          // s_part visible; red WAR-guard

            // cross-wave reduce + squash
            float sd = 0.f;
            if (t < D_DIM) {
#pragma unroll
                for (int w = 0; w < NW; ++w) sd += s_part[w][t];
            }
            const float ssn = block_sum_nb(sd * sd, red, wave, lane);

            // late prefetch of b+1: after the LAST barrier of r==2 so no
            // subsequent __syncthreads drains it except next k's loop-top
            // (by which time routing stores have covered its latency).
            if (r == 2 && k + 1 < NB)
                issue_prefetch(slab + N_CAP * D_DIM, pf, wave, lane);

            if (t < D_DIM) {
                const float scale = ssn / (1.0f + ssn) * rsqrtf(ssn + 1e-9f);
                const float vd = scale * sd;
                v_lds[t] = vd;
                if (r == 2) out_v[(size_t)b * D_DIM + t] = vd;
            }

            if (r < 2) {
                __syncthreads();                      // v_lds visible; red WAR-guard
                const float4 vv = *reinterpret_cast<const float4*>(&v_lds[lane * 4]);
                // agreement: b_n += (x_n . v) * inv_n (lane-0 owner-slot update)
#pragma unroll
                for (int i = 0; i < CPW; ++i) {
                    float p = fmaf(bf_lo(u[i].x), vv.x,
                              fmaf(bf_hi(u[i].x), vv.y,
                              fmaf(bf_lo(u[i].y), vv.z,
                                   bf_hi(u[i].y) * vv.w)));
                    p = wave_sum(p);
                    if (lane == 0) {
                        const int n = wave + NW * i;
                        b_lds[n] = fmaf(p, inv_lds[n], b_lds[n]);
                    }
                }
                __syncthreads();                      // b_lds visible for next iter
            }
        }
    }
}

extern "C" void kernel_launch(void* const* d_in, const int* in_sizes, int n_in,
                              void* d_out, int out_size, void* d_ws, size_t ws_size,
                              hipStream_t stream) {
    const float* embeds  = (const float*)d_in[0];
    const float* weights = (const float*)d_in[1];
    float* out   = (float*)d_out;
    float* out_v = out;                                  // [2048, 256]
    float* out_c = out + (size_t)B_TOT * D_DIM;          // [2048, 200]

    dyr_kernel<<<GRID, NT, 0, stream>>>(embeds, weights, out_v, out_c);
}

// Round 15
// 204.944 us; speedup vs baseline: 1.1823x; 1.1823x over previous
//
#include <hip/hip_runtime.h>
#include <hip/hip_bf16.h>

#define B_TOT 2048
#define N_CAP 200
#define D_DIM 256
#define NT    512
#define NW    8               // waves per block (routing kernel)
#define CPW   25              // capsules per wave (200/8, exact)
#define ROWS  (B_TOT * N_CAP) // 409600 normalize rows

__device__ __forceinline__ float bf_lo(unsigned u) { return __uint_as_float(u << 16); }
__device__ __forceinline__ float bf_hi(unsigned u) { return __uint_as_float(u & 0xffff0000u); }

__device__ __forceinline__ float wave_sum(float v) {
#pragma unroll
    for (int off = 32; off; off >>= 1) v += __shfl_xor(v, off);
    return v;
}

// Block sum WITHOUT leading barrier: caller must guarantee a __syncthreads()
// executed between the previous read of red[] and this call (WAR safety).
__device__ __forceinline__ float block_sum_nb(float v, float* red, int wave, int lane) {
    v = wave_sum(v);
    if (lane == 0) red[wave] = v;
    __syncthreads();
    float s = 0.f;
#pragma unroll
    for (int i = 0; i < NW; ++i) s += red[i];
    return s;
}

// ---------------- Pass 1: streaming normalize, f32 -> bf16 u_hat ----------------
// One wave per row. Pure BW kernel: no barriers, tiny register file.
__global__ __launch_bounds__(256)
void norm_kernel(const float* __restrict__ embeds, __hip_bfloat16* __restrict__ uhat)
{
    const int wave = threadIdx.x >> 6;
    const int lane = threadIdx.x & 63;
    const size_t row = (size_t)blockIdx.x * 4 + wave;   // ROWS % 4 == 0, no guard

    const float4 x = *reinterpret_cast<const float4*>(embeds + row * D_DIM + lane * 4);
    float ss = fmaf(x.x, x.x, fmaf(x.y, x.y, fmaf(x.z, x.z, x.w * x.w)));
    ss = wave_sum(ss);
    const float inv = 1.0f / fmaxf(sqrtf(ss), 1e-12f);
    union { __hip_bfloat16 h[4]; uint2 q; } pk;
    pk.h[0] = __float2bfloat16(x.x * inv);
    pk.h[1] = __float2bfloat16(x.y * inv);
    pk.h[2] = __float2bfloat16(x.z * inv);
    pk.h[3] = __float2bfloat16(x.w * inv);
    *reinterpret_cast<uint2*>(uhat + row * D_DIM + lane * 4) = pk.q;
}

// ---------------- Pass 2: routing (R10's proven phase layout, bf16 input) -------
// Loads are 4x smaller than R10's (bf16, 100 KB/block) and L3-warm (pass 1
// just wrote them) -> the load:routing phase alternation that capped R10
// shrinks. No normalize in the load loop (no wave_sum / inv_lds) -> peak regs
// u[25]=50 + 10 in-flight + temps ~ 64, honest fit at the allocator's point.
__global__ __launch_bounds__(NT, 4)
void route_kernel(const __hip_bfloat16* __restrict__ uhat,
                  const float* __restrict__ weights,
                  float* __restrict__ out_v,
                  float* __restrict__ out_c)
{
    __shared__ float s_part[NW][D_DIM];   // 8 KB
    __shared__ float red[NW];
    __shared__ float b_lds[N_CAP];        // routing logits
    __shared__ float w_lds[N_CAP];        // einsum weights c_n
    __shared__ float v_lds[D_DIM];

    const int b    = blockIdx.x;
    const int t    = threadIdx.x;
    const int wave = t >> 6;
    const int lane = t & 63;

    // ---- init logits (own slot; first read is by the same thread) ----
    if (t < N_CAP) b_lds[t] = weights[(size_t)b * N_CAP + t];

    // ---- Load u_hat bf16: wave w, lane l holds capsule n = w + 8i,
    // dims [4l, 4l+4). 5 chunks x 5 in-flight uint2 loads. ----
    const __hip_bfloat16* ub = uhat + (size_t)b * (N_CAP * D_DIM) + lane * 4;

    uint2 u[CPW];   // 50 VGPRs
#pragma unroll
    for (int cc = 0; cc < 5; ++cc) {
        uint2 xs[5];
#pragma unroll
        for (int j = 0; j < 5; ++j) {
            const int n = wave + (cc * 5 + j) * NW;
            xs[j] = *reinterpret_cast<const uint2*>(ub + n * D_DIM);
        }
#pragma unroll
        for (int j = 0; j < 5; ++j) u[cc * 5 + j] = xs[j];
    }

    // ---- 3 routing iterations (R10's exact phase layout) ----
    for (int r = 0; r < 3; ++r) {
        // softmax denominator (no max-subtraction; |b| <= ~8, fp32 exp safe)
        const float e  = (t < N_CAP) ? __expf(b_lds[t]) : 0.0f;
        const float es = block_sum_nb(e, red, wave, lane);
        const float cs = (float)N_CAP / es;
        if (t < N_CAP) {
            const float cv = e * cs;             // c_n = softmax * N
            w_lds[t] = cv;
            if (r == 2) out_c[(size_t)b * N_CAP + t] = cv;
        }
        __syncthreads();                          // w_lds visible

        // einsum partial: acc = sum_i c_i * u_i  (own capsules, w broadcast)
        float4 acc = make_float4(0.f, 0.f, 0.f, 0.f);
#pragma unroll
        for (int i = 0; i < CPW; ++i) {
            const float wn = w_lds[wave + NW * i];   // wave-uniform broadcast
            acc.x = fmaf(wn, bf_lo(u[i].x), acc.x);
            acc.y = fmaf(wn, bf_hi(u[i].x), acc.y);
            acc.z = fmaf(wn, bf_lo(u[i].y), acc.z);
            acc.w = fmaf(wn, bf_hi(u[i].y), acc.w);
        }
        *reinterpret_cast<float4*>(&s_part[wave][lane * 4]) = acc;
        __syncthreads();                          // s_part visible; red WAR-guard

        // cross-wave reduce + squash
        float sd = 0.f;
        if (t < D_DIM) {
#pragma unroll
            for (int w = 0; w < NW; ++w) sd += s_part[w][t];
        }
        const float ssn = block_sum_nb(sd * sd, red, wave, lane);
        if (t < D_DIM) {
            const float scale = ssn / (1.0f + ssn) * rsqrtf(ssn + 1e-9f);
            const float vd = scale * sd;
            v_lds[t] = vd;
            if (r == 2) out_v[(size_t)b * D_DIM + t] = vd;
        }

        if (r < 2) {
            __syncthreads();                      // v_lds visible; red WAR-guard
            const float4 vv = *reinterpret_cast<const float4*>(&v_lds[lane * 4]);
            // agreement: b_n += u_hat_n . v  (lane-0 owner-slot update)
#pragma unroll
            for (int i = 0; i < CPW; ++i) {
                float p = fmaf(bf_lo(u[i].x), vv.x,
                          fmaf(bf_hi(u[i].x), vv.y,
                          fmaf(bf_lo(u[i].y), vv.z,
                               bf_hi(u[i].y) * vv.w)));
                p = wave_sum(p);
                if (lane == 0) b_lds[wave + NW * i] += p;
            }
            __syncthreads();                      // b_lds visible for next iter
        }
    }
}

// ---------------- Fallback: R10 verbatim (162us, proven) ----------------
__global__ __launch_bounds__(NT, 4)
void dyr_kernel_r10(const float* __restrict__ embeds,
                    const float* __restrict__ weights,
                    float* __restrict__ out_v,
                    float* __restrict__ out_c)
{
    __shared__ float s_part[NW][D_DIM];
    __shared__ float red[NW];
    __shared__ float b_lds[N_CAP];
    __shared__ float w_lds[N_CAP];
    __shared__ float inv_lds[N_CAP];
    __shared__ float v_lds[D_DIM];

    const int b    = blockIdx.x;
    const int t    = threadIdx.x;
    const int wave = t >> 6;
    const int lane = t & 63;

    if (t < N_CAP) b_lds[t] = weights[(size_t)b * N_CAP + t];

    const float* eb = embeds + (size_t)b * (N_CAP * D_DIM) + lane * 4;
    uint2 u[CPW];
#pragma unroll
    for (int cc = 0; cc < 5; ++cc) {
        float4 xs[5];
#pragma unroll
        for (int j = 0; j < 5; ++j) {
            const int n = wave + (cc * 5 + j) * NW;
            xs[j] = *reinterpret_cast<const float4*>(eb + n * D_DIM);
        }
#pragma unroll
        for (int j = 0; j < 5; ++j) {
            const float4 x = xs[j];
            float ss = fmaf(x.x, x.x, fmaf(x.y, x.y, fmaf(x.z, x.z, x.w * x.w)));
            ss = wave_sum(ss);
            if (lane == 0)
                inv_lds[wave + (cc * 5 + j) * NW] = 1.0f / fmaxf(sqrtf(ss), 1e-12f);
            union { __hip_bfloat16 h[4]; uint2 q; } pk;
            pk.h[0] = __float2bfloat16(x.x);
            pk.h[1] = __float2bfloat16(x.y);
            pk.h[2] = __float2bfloat16(x.z);
            pk.h[3] = __float2bfloat16(x.w);
            u[cc * 5 + j] = pk.q;
        }
    }
    __syncthreads();

    for (int r = 0; r < 3; ++r) {
        const float e  = (t < N_CAP) ? __expf(b_lds[t]) : 0.0f;
        const float es = block_sum_nb(e, red, wave, lane);
        const float cs = (float)N_CAP / es;
        if (t < N_CAP) {
            const float cv = e * cs;
            w_lds[t] = cv * inv_lds[t];
            if (r == 2) out_c[(size_t)b * N_CAP + t] = cv;
        }
        __syncthreads();

        float4 acc = make_float4(0.f, 0.f, 0.f, 0.f);
#pragma unroll
        for (int i = 0; i < CPW; ++i) {
            const float wn = w_lds[wave + NW * i];
            acc.x = fmaf(wn, bf_lo(u[i].x), acc.x);
            acc.y = fmaf(wn, bf_hi(u[i].x), acc.y);
            acc.z = fmaf(wn, bf_lo(u[i].y), acc.z);
            acc.w = fmaf(wn, bf_hi(u[i].y), acc.w);
        }
        *reinterpret_cast<float4*>(&s_part[wave][lane * 4]) = acc;
        __syncthreads();

        float sd = 0.f;
        if (t < D_DIM) {
#pragma unroll
            for (int w = 0; w < NW; ++w) sd += s_part[w][t];
        }
        const float ssn = block_sum_nb(sd * sd, red, wave, lane);
        if (t < D_DIM) {
            const float scale = ssn / (1.0f + ssn) * rsqrtf(ssn + 1e-9f);
            const float vd = scale * sd;
            v_lds[t] = vd;
            if (r == 2) out_v[(size_t)b * D_DIM + t] = vd;
        }

        if (r < 2) {
            __syncthreads();
            const float4 vv = *reinterpret_cast<const float4*>(&v_lds[lane * 4]);
#pragma unroll
            for (int i = 0; i < CPW; ++i) {
                float p = fmaf(bf_lo(u[i].x), vv.x,
                          fmaf(bf_hi(u[i].x), vv.y,
                          fmaf(bf_lo(u[i].y), vv.z,
                               bf_hi(u[i].y) * vv.w)));
                p = wave_sum(p);
                if (lane == 0) {
                    const int n = wave + NW * i;
                    b_lds[n] = fmaf(p, inv_lds[n], b_lds[n]);
                }
            }
            __syncthreads();
        }
    }
}

extern "C" void kernel_launch(void* const* d_in, const int* in_sizes, int n_in,
                              void* d_out, int out_size, void* d_ws, size_t ws_size,
                              hipStream_t stream) {
    const float* embeds  = (const float*)d_in[0];
    const float* weights = (const float*)d_in[1];
    float* out   = (float*)d_out;
    float* out_v = out;                                  // [2048, 256]
    float* out_c = out + (size_t)B_TOT * D_DIM;          // [2048, 200]

    const size_t need = (size_t)B_TOT * N_CAP * D_DIM * sizeof(__hip_bfloat16);
    if (ws_size >= need) {
        __hip_bfloat16* uhat = (__hip_bfloat16*)d_ws;
        norm_kernel<<<ROWS / 4, 256, 0, stream>>>(embeds, uhat);
        route_kernel<<<B_TOT, NT, 0, stream>>>(uhat, weights, out_v, out_c);
    } else {
        dyr_kernel_r10<<<B_TOT, NT, 0, stream>>>(embeds, weights, out_v, out_c);
    }
}

// Round 16
// 166.015 us; speedup vs baseline: 1.4596x; 1.2345x over previous
//
#include <hip/hip_runtime.h>
#include <hip/hip_bf16.h>

#define B_TOT 2048
#define N_CAP 200
#define D_DIM 256
#define NT    512
#define NW    8               // waves per block
#define CPW   25              // capsules per wave (200/8, exact)

__device__ __forceinline__ float bf_lo(unsigned u) { return __uint_as_float(u << 16); }
__device__ __forceinline__ float bf_hi(unsigned u) { return __uint_as_float(u & 0xffff0000u); }

__device__ __forceinline__ float wave_sum(float v) {
#pragma unroll
    for (int off = 32; off; off >>= 1) v += __shfl_xor(v, off);
    return v;
}

// Block sum WITHOUT leading barrier: caller must guarantee a __syncthreads()
// executed between the previous read of red[] and this call (WAR safety).
__device__ __forceinline__ float block_sum_nb(float v, float* red, int wave, int lane) {
    v = wave_sum(v);
    if (lane == 0) red[wave] = v;
    __syncthreads();
    float s = 0.f;
#pragma unroll
    for (int i = 0; i < NW; ++i) s += red[i];
    return s;
}

// Anchor = R10 (162us, best). R16 delta (load-phase only): split the load
// loop into Phase A {pure float4-load -> bf16-pack stream; ~40cy between
// chunks} and Phase B {norms computed FROM the packed bf16 regs: 25
// independent unpack+FMA+wave_sum chains}. R10 ran 5 serial wave_sum chains
// (~500cy dependent VALU) between chunks, gating next-chunk load issue.
// Norm-from-bf16 adds <=0.4% rel error to u_hat (absmax 0.5 -> ~0.7 max,
// threshold 2.47). Routing phases byte-identical to R10.
// DO NOT: fuse agreement+einsum accumulators (R3/R4 spill), LB(...,8)
// (R9: 32 VGPR), per-capsule sched_barrier (R6), LDS-split u (R7),
// lane-select psel gather (R11 wrong c), phase-cut tails / inline e*inv
// (R12 +19us), 16-wave split (R13 +16us), persistent+DMA-prefetch (R14
// +80us), two-pass normalize (R15 +43us).
__global__ __launch_bounds__(NT, 4)
void dyr_kernel(const float* __restrict__ embeds,
                const float* __restrict__ weights,
                float* __restrict__ out_v,
                float* __restrict__ out_c)
{
    __shared__ float s_part[NW][D_DIM];   // 8 KB
    __shared__ float red[NW];
    __shared__ float b_lds[N_CAP];        // routing logits
    __shared__ float w_lds[N_CAP];        // einsum weights c_n * inv_n
    __shared__ float inv_lds[N_CAP];      // 1 / max(||x_n||, 1e-12)
    __shared__ float v_lds[D_DIM];

    const int b    = blockIdx.x;
    const int t    = threadIdx.x;
    const int wave = t >> 6;
    const int lane = t & 63;

    // ---- init logits ----
    if (t < N_CAP) b_lds[t] = weights[(size_t)b * N_CAP + t];

    // ---- Phase A: load embeds ONCE, pack raw bf16 -> u[] (pure stream).
    // wave w, lane l holds capsule n = w + 8i, dims [4l, 4l+4).
    // 5 chunks x 5 in-flight float4 loads (R2/R10's proven depth); the only
    // VALU between chunks is 20 cvt ops. ----
    const float* eb = embeds + (size_t)b * (N_CAP * D_DIM) + lane * 4;

    uint2 u[CPW];   // 50 VGPRs, raw x packed bf16
#pragma unroll
    for (int cc = 0; cc < 5; ++cc) {
        float4 xs[5];
#pragma unroll
        for (int j = 0; j < 5; ++j) {
            const int n = wave + (cc * 5 + j) * NW;
            xs[j] = *reinterpret_cast<const float4*>(eb + n * D_DIM);
        }
#pragma unroll
        for (int j = 0; j < 5; ++j) {
            union { __hip_bfloat16 h[4]; uint2 q; } pk;
            pk.h[0] = __float2bfloat16(xs[j].x);
            pk.h[1] = __float2bfloat16(xs[j].y);
            pk.h[2] = __float2bfloat16(xs[j].z);
            pk.h[3] = __float2bfloat16(xs[j].w);
            u[cc * 5 + j] = pk.q;
        }
    }

    // ---- Phase B: norms from the packed bf16 registers (25 independent
    // chains; no loads are waiting on these) ----
#pragma unroll
    for (int i = 0; i < CPW; ++i) {
        const float a0 = bf_lo(u[i].x), a1 = bf_hi(u[i].x);
        const float a2 = bf_lo(u[i].y), a3 = bf_hi(u[i].y);
        float ss = fmaf(a0, a0, fmaf(a1, a1, fmaf(a2, a2, a3 * a3)));
        ss = wave_sum(ss);
        if (lane == 0)
            inv_lds[wave + NW * i] = 1.0f / fmaxf(sqrtf(ss), 1e-12f);
    }
    __syncthreads();   // inv_lds/b_lds visible; WAR-guard for first block_sum_nb

    // ---- 3 routing iterations (R10's exact phase layout) ----
    for (int r = 0; r < 3; ++r) {
        // softmax denominator (no max-subtraction; |b| <= ~8, fp32 exp safe)
        const float e  = (t < N_CAP) ? __expf(b_lds[t]) : 0.0f;
        const float es = block_sum_nb(e, red, wave, lane);
        const float cs = (float)N_CAP / es;
        if (t < N_CAP) {
            const float cv = e * cs;             // c_n = softmax * N
            w_lds[t] = cv * inv_lds[t];          // einsum weight (norm folded)
            if (r == 2) out_c[(size_t)b * N_CAP + t] = cv;
        }
        __syncthreads();                          // w_lds visible

        // einsum partial: acc = sum_i w_i * x_i  (own capsules, w broadcast)
        float4 acc = make_float4(0.f, 0.f, 0.f, 0.f);
#pragma unroll
        for (int i = 0; i < CPW; ++i) {
            const float wn = w_lds[wave + NW * i];   // wave-uniform broadcast
            acc.x = fmaf(wn, bf_lo(u[i].x), acc.x);
            acc.y = fmaf(wn, bf_hi(u[i].x), acc.y);
            acc.z = fmaf(wn, bf_lo(u[i].y), acc.z);
            acc.w = fmaf(wn, bf_hi(u[i].y), acc.w);
        }
        *reinterpret_cast<float4*>(&s_part[wave][lane * 4]) = acc;
        __syncthreads();                          // s_part visible; red WAR-guard

        // cross-wave reduce + squash
        float sd = 0.f;
        if (t < D_DIM) {
#pragma unroll
            for (int w = 0; w < NW; ++w) sd += s_part[w][t];
        }
        const float ssn = block_sum_nb(sd * sd, red, wave, lane);
        if (t < D_DIM) {
            const float scale = ssn / (1.0f + ssn) * rsqrtf(ssn + 1e-9f);
            const float vd = scale * sd;
            v_lds[t] = vd;
            if (r == 2) out_v[(size_t)b * D_DIM + t] = vd;
        }

        if (r < 2) {
            __syncthreads();                      // v_lds visible; red WAR-guard
            const float4 vv = *reinterpret_cast<const float4*>(&v_lds[lane * 4]);
            // agreement: b_n += (x_n . v) * inv_n  (lane-0 owner-slot update)
#pragma unroll
            for (int i = 0; i < CPW; ++i) {
                float p = fmaf(bf_lo(u[i].x), vv.x,
                          fmaf(bf_hi(u[i].x), vv.y,
                          fmaf(bf_lo(u[i].y), vv.z,
                               bf_hi(u[i].y) * vv.w)));
                p = wave_sum(p);
                if (lane == 0) {
                    const int n = wave + NW * i;
                    b_lds[n] = fmaf(p, inv_lds[n], b_lds[n]);
                }
            }
            __syncthreads();                      // b_lds visible for next iter
        }
    }
}

extern "C" void kernel_launch(void* const* d_in, const int* in_sizes, int n_in,
                              void* d_out, int out_size, void* d_ws, size_t ws_size,
                              hipStream_t stream) {
    const float* embeds  = (const float*)d_in[0];
    const float* weights = (const float*)d_in[1];
    float* out   = (float*)d_out;
    float* out_v = out;                                  // [2048, 256]
    float* out_c = out + (size_t)B_TOT * D_DIM;          // [2048, 200]

    dyr_kernel<<<B_TOT, NT, 0, stream>>>(embeds, weights, out_v, out_c);
}

// Round 17
// 156.905 us; speedup vs baseline: 1.5443x; 1.0581x over previous
//
#include <hip/hip_runtime.h>
#include <hip/hip_bf16.h>

#define B_TOT 2048
#define N_CAP 200
#define D_DIM 256
#define NT    512
#define NW    8               // waves per block
#define CPW   25              // capsules per wave (200/8, exact)

__device__ __forceinline__ float bf_lo(unsigned u) { return __uint_as_float(u << 16); }
__device__ __forceinline__ float bf_hi(unsigned u) { return __uint_as_float(u & 0xffff0000u); }

__device__ __forceinline__ float wave_sum(float v) {
#pragma unroll
    for (int off = 32; off; off >>= 1) v += __shfl_xor(v, off);
    return v;
}

// Block sum WITHOUT leading barrier: caller must guarantee a __syncthreads()
// executed between the previous read of red[] and this call (WAR safety).
__device__ __forceinline__ float block_sum_nb(float v, float* red, int wave, int lane) {
    v = wave_sum(v);
    if (lane == 0) red[wave] = v;
    __syncthreads();
    float s = 0.f;
#pragma unroll
    for (int i = 0; i < NW; ++i) s += red[i];
    return s;
}

// Anchor = R10 (162us, best). R17 sole delta: WAVE-REDUNDANT SQUASH.
// Each lane's sd float4 covers dims [4l,4l+4) -> one wave spans all 256 dims,
// so ssn = wave_sum(|sd|^2) is the full norm with NO cross-wave reduce.
// Deletes v_lds + its publish barrier + the ssn block_sum: 17 -> 11 barriers.
// Pattern correctness-proven in R3-R5 (passed; their losses were spill).
// DO NOT: fuse agreement+einsum accumulators (R3/R4 spill), LB(...,8)
// (R9: 32 VGPR), per-capsule sched_barrier (R6), LDS-split u (R7),
// lane-select psel gather (R11 wrong c), phase-cut tails / inline e*inv
// (R12 +19us), 16-wave split (R13 +16us), persistent+DMA prefetch (R14),
// two-pass normalize (R15), load/norm phase split (R16 neutral).
__global__ __launch_bounds__(NT, 4)
void dyr_kernel(const float* __restrict__ embeds,
                const float* __restrict__ weights,
                float* __restrict__ out_v,
                float* __restrict__ out_c)
{
    __shared__ float s_part[NW][D_DIM];   // 8 KB
    __shared__ float red[NW];
    __shared__ float b_lds[N_CAP];        // routing logits
    __shared__ float w_lds[N_CAP];        // einsum weights c_n * inv_n
    __shared__ float inv_lds[N_CAP];      // 1 / max(||x_n||, 1e-12)

    const int b    = blockIdx.x;
    const int t    = threadIdx.x;
    const int wave = t >> 6;
    const int lane = t & 63;

    // ---- init logits ----
    if (t < N_CAP) b_lds[t] = weights[(size_t)b * N_CAP + t];

    // ---- Load embeds ONCE; RAW x -> bf16 regs; 1/||x|| -> LDS.
    // wave w, lane l holds capsule n = w + 8i, dims [4l, 4l+4).
    // 5 chunks x 5 in-flight float4 loads (R2/R10's proven schedule). ----
    const float* eb = embeds + (size_t)b * (N_CAP * D_DIM) + lane * 4;

    uint2 u[CPW];   // 50 VGPRs, raw x packed bf16
#pragma unroll
    for (int cc = 0; cc < 5; ++cc) {
        float4 xs[5];
#pragma unroll
        for (int j = 0; j < 5; ++j) {
            const int n = wave + (cc * 5 + j) * NW;
            xs[j] = *reinterpret_cast<const float4*>(eb + n * D_DIM);
        }
#pragma unroll
        for (int j = 0; j < 5; ++j) {
            const float4 x = xs[j];
            float ss = fmaf(x.x, x.x, fmaf(x.y, x.y, fmaf(x.z, x.z, x.w * x.w)));
            ss = wave_sum(ss);
            if (lane == 0)
                inv_lds[wave + (cc * 5 + j) * NW] = 1.0f / fmaxf(sqrtf(ss), 1e-12f);
            union { __hip_bfloat16 h[4]; uint2 q; } pk;
            pk.h[0] = __float2bfloat16(x.x);
            pk.h[1] = __float2bfloat16(x.y);
            pk.h[2] = __float2bfloat16(x.z);
            pk.h[3] = __float2bfloat16(x.w);
            u[cc * 5 + j] = pk.q;
        }
    }
    __syncthreads();   // inv_lds/b_lds visible; WAR-guard for first block_sum_nb

    // ---- 3 routing iterations ----
    for (int r = 0; r < 3; ++r) {
        // softmax denominator (no max-subtraction; |b| <= ~8, fp32 exp safe)
        const float e  = (t < N_CAP) ? __expf(b_lds[t]) : 0.0f;
        const float es = block_sum_nb(e, red, wave, lane);          // B1
        const float cs = (float)N_CAP / es;
        if (t < N_CAP) {
            const float cv = e * cs;             // c_n = softmax * N
            w_lds[t] = cv * inv_lds[t];          // einsum weight (norm folded)
            if (r == 2) out_c[(size_t)b * N_CAP + t] = cv;
        }
        __syncthreads();                          // B2: w_lds visible

        // einsum partial: acc = sum_i w_i * x_i  (own capsules, w broadcast)
        float4 acc = make_float4(0.f, 0.f, 0.f, 0.f);
#pragma unroll
        for (int i = 0; i < CPW; ++i) {
            const float wn = w_lds[wave + NW * i];   // wave-uniform broadcast
            acc.x = fmaf(wn, bf_lo(u[i].x), acc.x);
            acc.y = fmaf(wn, bf_hi(u[i].x), acc.y);
            acc.z = fmaf(wn, bf_lo(u[i].y), acc.z);
            acc.w = fmaf(wn, bf_hi(u[i].y), acc.w);
        }
        *reinterpret_cast<float4*>(&s_part[wave][lane * 4]) = acc;
        __syncthreads();                          // B3: s_part visible

        // WAVE-REDUNDANT squash: this wave's 64 lanes span all 256 dims,
        // so wave_sum of |sd|^2 is the full ssn. No block reduce, no v_lds.
        float4 sd = make_float4(0.f, 0.f, 0.f, 0.f);
#pragma unroll
        for (int w = 0; w < NW; ++w) {
            const float4 p = *reinterpret_cast<const float4*>(&s_part[w][lane * 4]);
            sd.x += p.x; sd.y += p.y; sd.z += p.z; sd.w += p.w;
        }
        float ssn = fmaf(sd.x, sd.x, fmaf(sd.y, sd.y, fmaf(sd.z, sd.z, sd.w * sd.w)));
        ssn = wave_sum(ssn);
        const float scale = ssn / (1.0f + ssn) * rsqrtf(ssn + 1e-9f);
        const float4 vv = make_float4(scale * sd.x, scale * sd.y,
                                      scale * sd.z, scale * sd.w);

        if (r == 2) {
            if (wave == 0)
                *reinterpret_cast<float4*>(&out_v[(size_t)b * D_DIM + lane * 4]) = vv;
        } else {
            // agreement: b_n += (x_n . v) * inv_n  (lane-0 owner-slot update);
            // vv is in registers — no LDS read, no extra barrier before this.
#pragma unroll
            for (int i = 0; i < CPW; ++i) {
                float p = fmaf(bf_lo(u[i].x), vv.x,
                          fmaf(bf_hi(u[i].x), vv.y,
                          fmaf(bf_lo(u[i].y), vv.z,
                               bf_hi(u[i].y) * vv.w)));
                p = wave_sum(p);
                if (lane == 0) {
                    const int n = wave + NW * i;
                    b_lds[n] = fmaf(p, inv_lds[n], b_lds[n]);
                }
            }
            __syncthreads();                      // B4: b_lds visible for next iter
        }
    }
}

extern "C" void kernel_launch(void* const* d_in, const int* in_sizes, int n_in,
                              void* d_out, int out_size, void* d_ws, size_t ws_size,
                              hipStream_t stream) {
    const float* embeds  = (const float*)d_in[0];
    const float* weights = (const float*)d_in[1];
    float* out   = (float*)d_out;
    float* out_v = out;                                  // [2048, 256]
    float* out_c = out + (size_t)B_TOT * D_DIM;          // [2048, 200]

    dyr_kernel<<<B_TOT, NT, 0, stream>>>(embeds, weights, out_v, out_c);
}